// Round 5
// baseline (22.570 us; speedup 1.0000x reference)
//
#include <hip/hip_runtime.h>
#include <math.h>

// BatchAllTripletLoss — G-free fused formulation.
// batch = concat(h1,h2) : (512, 256) f32.
// Masked triplet only at k=j^256:
//   t(i,j) = relu(d(i,j) - d(i,j^256) + 1)
//          = relu((sq_j - sq_jp) - 2*(dot_ij - dot_ijp) + 1)   [sq_i cancels]
// The 1e-7 clamp on d only affects i==j / i==j^256 diagonal entries, whose
// relu argument is ~ -500 (dead) or ~ +500 (clamp shifts by <=3e-4) => safe.
// outputs (5 x f32): loss, mean(differences)=0 (exact cancellation), good, bad, sqrt(mean(sq))
//
// K1 sq (512x64), K2 gramstats (256x128: 32 A-rows x (16+16 pair-closed cols),
// 2x4 micro-tile, 3B/MAC LDS intensity), K3 finalize (1x512).
// Round-3 lesson kept: no device fences; kernel boundaries provide ordering.

#define S4 65   // float4 stride per LDS row (260 floats): pad + XOR swizzle

__device__ __forceinline__ const float* batch_row(const float* __restrict__ h1,
                                                  const float* __restrict__ h2,
                                                  int r) {
    return (r < 256) ? (h1 + (size_t)r * 256) : (h2 + (size_t)(r - 256) * 256);
}

// XOR-swizzled float4 index (same involution on write and read; 0 conflicts
// measured in rounds 3/4).
__device__ __forceinline__ int lds4(int row, int c4) {
    return row * S4 + (c4 ^ ((row >> 1) & 15));
}

__device__ __forceinline__ float hsum4(float4 v) { return (v.x + v.y) + (v.z + v.w); }

// --- K1: squared norms of all 512 rows -----------------------------------
__global__ __launch_bounds__(64) void sq_kernel(const float* __restrict__ h1,
                                                const float* __restrict__ h2,
                                                float* __restrict__ sq) {
    const int r = blockIdx.x;        // 0..511
    const int lane = threadIdx.x;    // 0..63
    float4 v = reinterpret_cast<const float4*>(batch_row(h1, h2, r))[lane];
    float s = v.x * v.x + v.y * v.y + v.z * v.z + v.w * v.w;
#pragma unroll
    for (int off = 32; off > 0; off >>= 1) s += __shfl_down(s, off);
    if (lane == 0) sq[r] = s;
}

// --- K2: fused Gram + pair stats (no G materialization) -------------------
__global__ __launch_bounds__(128) void gramstats_kernel(const float* __restrict__ h1,
                                                        const float* __restrict__ h2,
                                                        const float* __restrict__ sq,
                                                        float* __restrict__ partials) {
    const int ib = blockIdx.x >> 4;  // 0..15 -> A rows 32ib..32ib+31
    const int jb = blockIdx.x & 15;  // 0..15 -> cols [16jb,16jb+16) U +256
    const int t  = threadIdx.x;      // 0..127

    __shared__ __align__(16) float4 Af[32 * S4];  // 32 A-rows
    __shared__ __align__(16) float4 Bf[32 * S4];  // 16 tile0 rows + 16 tile1 rows
    __shared__ float red[3][2];

    // stage A (wave-uniform row per pass, coalesced 1KB/wave)
#pragma unroll
    for (int p = 0; p < 16; ++p) {
        const int idx = p * 128 + t;
        const int row = idx >> 6, c4 = idx & 63;
        Af[lds4(row, c4)] = reinterpret_cast<const float4*>(batch_row(h1, h2, ib * 32 + row))[c4];
    }
    // stage B: rows 0..15 -> cols 16jb+row; rows 16..31 -> cols 16jb+row+240 (=+256)
#pragma unroll
    for (int p = 0; p < 16; ++p) {
        const int idx = p * 128 + t;
        const int row = idx >> 6, c4 = idx & 63;
        const int col = jb * 16 + ((row < 16) ? row : row + 240);
        Bf[lds4(row, c4)] = reinterpret_cast<const float4*>(batch_row(h1, h2, col))[c4];
    }
    __syncthreads();

    const int ty = t >> 3;           // 0..15 -> A rows 2ty, 2ty+1
    const int cx = t & 7;            // 0..7  -> B rows 2cx,2cx+1 (tile0), +16 (tile1)
    const int ba0 = (2 * ty) * S4;
    const int bb0 = (2 * cx) * S4;
    const int bb1 = (16 + 2 * cx) * S4;

    float4 a00 = make_float4(0.f, 0.f, 0.f, 0.f);  // acc[row r][bcol c]
    float4 a01 = a00, a02 = a00, a03 = a00;
    float4 a10 = a00, a11 = a00, a12 = a00, a13 = a00;

#pragma unroll 8
    for (int k4 = 0; k4 < 64; ++k4) {
        const int ea = k4 ^ ty;          // mask for A rows 2ty,2ty+1: (row>>1)&15 = ty
        const int eb = k4 ^ cx;          // mask for B rows 2cx,2cx+1
        const int ec = eb ^ 8;           // mask for rows 16+2cx..: k4^(8+cx) = eb^8
        const float4 va0 = Af[ba0 + ea];
        const float4 va1 = Af[ba0 + S4 + ea];
        const float4 b0  = Bf[bb0 + eb];
        const float4 b1  = Bf[bb0 + S4 + eb];
        const float4 b2  = Bf[bb1 + ec];
        const float4 b3  = Bf[bb1 + S4 + ec];

        a00.x = fmaf(va0.x, b0.x, a00.x); a00.y = fmaf(va0.y, b0.y, a00.y);
        a00.z = fmaf(va0.z, b0.z, a00.z); a00.w = fmaf(va0.w, b0.w, a00.w);
        a01.x = fmaf(va0.x, b1.x, a01.x); a01.y = fmaf(va0.y, b1.y, a01.y);
        a01.z = fmaf(va0.z, b1.z, a01.z); a01.w = fmaf(va0.w, b1.w, a01.w);
        a02.x = fmaf(va0.x, b2.x, a02.x); a02.y = fmaf(va0.y, b2.y, a02.y);
        a02.z = fmaf(va0.z, b2.z, a02.z); a02.w = fmaf(va0.w, b2.w, a02.w);
        a03.x = fmaf(va0.x, b3.x, a03.x); a03.y = fmaf(va0.y, b3.y, a03.y);
        a03.z = fmaf(va0.z, b3.z, a03.z); a03.w = fmaf(va0.w, b3.w, a03.w);
        a10.x = fmaf(va1.x, b0.x, a10.x); a10.y = fmaf(va1.y, b0.y, a10.y);
        a10.z = fmaf(va1.z, b0.z, a10.z); a10.w = fmaf(va1.w, b0.w, a10.w);
        a11.x = fmaf(va1.x, b1.x, a11.x); a11.y = fmaf(va1.y, b1.y, a11.y);
        a11.z = fmaf(va1.z, b1.z, a11.z); a11.w = fmaf(va1.w, b1.w, a11.w);
        a12.x = fmaf(va1.x, b2.x, a12.x); a12.y = fmaf(va1.y, b2.y, a12.y);
        a12.z = fmaf(va1.z, b2.z, a12.z); a12.w = fmaf(va1.w, b2.w, a12.w);
        a13.x = fmaf(va1.x, b3.x, a13.x); a13.y = fmaf(va1.y, b3.y, a13.y);
        a13.z = fmaf(va1.z, b3.z, a13.z); a13.w = fmaf(va1.w, b3.w, a13.w);
    }

    // dots: s[r][c]; c=0,1 tile0 cols (j0,j0+1); c=2,3 tile1 (pairs)
    const float s00 = hsum4(a00), s01 = hsum4(a01), s02 = hsum4(a02), s03 = hsum4(a03);
    const float s10 = hsum4(a10), s11 = hsum4(a11), s12 = hsum4(a12), s13 = hsum4(a13);

    const int j0 = jb * 16 + 2 * cx;
    const float dsq0 = sq[j0]     - sq[j0 + 256];   // sq_j - sq_jpair, col 0
    const float dsq1 = sq[j0 + 1] - sq[j0 + 257];   // col 1

    float srel = 0.f, crel = 0.f, good = 0.f;
    // r=0,c=0
    {
        const float diff = dsq0 - 2.f * (s00 - s02);
        const float tj = fmaxf(diff + 1.f, 0.f);    // entry (i, j)
        const float tp = fmaxf(1.f - diff, 0.f);    // entry (i, j^256)
        srel += (tj > 1e-5f ? tj : 0.f) + (tp > 1e-5f ? tp : 0.f);
        crel += (float)((tj > 1e-5f) + (tp > 1e-5f));
        good += (float)((tj < 1e-5f) + (tp < 1e-5f));
    }
    // r=0,c=1
    {
        const float diff = dsq1 - 2.f * (s01 - s03);
        const float tj = fmaxf(diff + 1.f, 0.f);
        const float tp = fmaxf(1.f - diff, 0.f);
        srel += (tj > 1e-5f ? tj : 0.f) + (tp > 1e-5f ? tp : 0.f);
        crel += (float)((tj > 1e-5f) + (tp > 1e-5f));
        good += (float)((tj < 1e-5f) + (tp < 1e-5f));
    }
    // r=1,c=0
    {
        const float diff = dsq0 - 2.f * (s10 - s12);
        const float tj = fmaxf(diff + 1.f, 0.f);
        const float tp = fmaxf(1.f - diff, 0.f);
        srel += (tj > 1e-5f ? tj : 0.f) + (tp > 1e-5f ? tp : 0.f);
        crel += (float)((tj > 1e-5f) + (tp > 1e-5f));
        good += (float)((tj < 1e-5f) + (tp < 1e-5f));
    }
    // r=1,c=1
    {
        const float diff = dsq1 - 2.f * (s11 - s13);
        const float tj = fmaxf(diff + 1.f, 0.f);
        const float tp = fmaxf(1.f - diff, 0.f);
        srel += (tj > 1e-5f ? tj : 0.f) + (tp > 1e-5f ? tp : 0.f);
        crel += (float)((tj > 1e-5f) + (tp > 1e-5f));
        good += (float)((tj < 1e-5f) + (tp < 1e-5f));
    }

#pragma unroll
    for (int off = 32; off > 0; off >>= 1) {
        srel += __shfl_down(srel, off);
        crel += __shfl_down(crel, off);
        good += __shfl_down(good, off);
    }
    const int w = t >> 6;  // 0..1
    if ((t & 63) == 0) { red[0][w] = srel; red[1][w] = crel; red[2][w] = good; }
    __syncthreads();
    if (t == 0) {
        reinterpret_cast<float4*>(partials)[blockIdx.x] =
            make_float4(red[0][0] + red[0][1], red[1][0] + red[1][1], red[2][0] + red[2][1], 0.f);
    }
}

// --- K3: final reduction + all 5 outputs ----------------------------------
__global__ __launch_bounds__(512) void finalize_kernel(const float* __restrict__ sq,
                                                       const float* __restrict__ partials,
                                                       float* __restrict__ out) {
    const int t = threadIdx.x;   // 0..511
    float4 pv = make_float4(0.f, 0.f, 0.f, 0.f);
    if (t < 256) pv = reinterpret_cast<const float4*>(partials)[t];
    float s = pv.x, c = pv.y, g = pv.z, q = sq[t];
#pragma unroll
    for (int off = 32; off > 0; off >>= 1) {
        s += __shfl_down(s, off);
        c += __shfl_down(c, off);
        g += __shfl_down(g, off);
        q += __shfl_down(q, off);
    }
    __shared__ float red[4][8];
    const int w = t >> 6;
    if ((t & 63) == 0) { red[0][w] = s; red[1][w] = c; red[2][w] = g; red[3][w] = q; }
    __syncthreads();
    if (t == 0) {
        float ss = 0.f, cc = 0.f, gg = 0.f, qq = 0.f;
#pragma unroll
        for (int k = 0; k < 8; ++k) { ss += red[0][k]; cc += red[1][k]; gg += red[2][k]; qq += red[3][k]; }
        const float mean_sq  = qq / 512.0f;
        const float mean_rel = ss / cc;
        const float goodTot  = 133955584.0f + gg;   // (512^3 - 512^2) + good_masked
        out[0] = mean_rel + 1e-4f * mean_sq;        // loss
        out[1] = 0.0f;                              // mean(differences): exact cancellation
        out[2] = goodTot;                           // good
        out[3] = 134217728.0f - goodTot;            // bad
        out[4] = sqrtf(mean_sq);                    // sqrt(mean norm^2)
    }
}

extern "C" void kernel_launch(void* const* d_in, const int* in_sizes, int n_in,
                              void* d_out, int out_size, void* d_ws, size_t ws_size,
                              hipStream_t stream) {
    (void)in_sizes; (void)n_in; (void)out_size; (void)ws_size;
    const float* h1 = (const float*)d_in[0];
    const float* h2 = (const float*)d_in[1];
    // d_in[2] (h3) unused by the reference forward.
    char* ws = (char*)d_ws;
    float* sq       = (float*)ws;              // 512 floats
    float* partials = (float*)(ws + 4096);     // 256 x float4
    float* out      = (float*)d_out;

    sq_kernel       <<<512, 64,  0, stream>>>(h1, h2, sq);
    gramstats_kernel<<<256, 128, 0, stream>>>(h1, h2, sq, partials);
    finalize_kernel <<<1,   512, 0, stream>>>(sq, partials, out);
}

// Round 6
// 14.653 us; speedup vs baseline: 1.5402x; 1.5402x over previous
//
#include <hip/hip_runtime.h>
#include <math.h>

// BatchAllTripletLoss — G-free, pair-fused, round-4 proven GEMM engine.
// batch = concat(h1,h2) : (512, 256) f32.
// Masked triplet only at k=j^256:
//   t(i,j) = relu(d(i,j) - d(i,j^256) + 1)
//          = relu((sq_j - sq_jp) - 2*(dot_ij - dot_ijp) + 1)   [sq_i cancels]
// Diagonal clamp (1e-7) effects are <=1e-7 on dead/huge entries => safe
// (verified rounds 4/5: absmax 7.45e-9).
// outputs: loss, mean(differences)=0 (exact cancellation), good, bad, sqrt(mean(sq))
//
// Lessons encoded:
//  r3: no __threadfence/atomic finalize (cost ~40us) -> separate tiny kernel.
//  r5: keep >=4 waves/block at 1 block/CU; 2-wave blocks are latency-bound.
// Block: 256 thr, A-tile 32 rows, B-tile = 16 j-cols + their 16 pairs.
// Pair partner = lane^8 -> __shfl_xor(dot, 8). ib==0 blocks emit global sq.

#define S4 65   // float4 stride per LDS row: pad + XOR swizzle (0 conflicts, r3/r4)

__device__ __forceinline__ const float* batch_row(const float* __restrict__ h1,
                                                  const float* __restrict__ h2,
                                                  int r) {
    return (r < 256) ? (h1 + (size_t)r * 256) : (h2 + (size_t)(r - 256) * 256);
}

// XOR-swizzled float4 index (same involution on write and read)
__device__ __forceinline__ int lds4(int row, int c4) {
    return row * S4 + (c4 ^ ((row >> 1) & 15));
}

__device__ __forceinline__ float hsum4(float4 v) { return (v.x + v.y) + (v.z + v.w); }

// --- K1: fused Gram + pair stats + sq emission ----------------------------
__global__ __launch_bounds__(256) void gramstats_kernel(const float* __restrict__ h1,
                                                        const float* __restrict__ h2,
                                                        float* __restrict__ sq,
                                                        float* __restrict__ partials) {
    const int ib = blockIdx.x >> 4;  // 0..15 -> A rows 32ib..32ib+31
    const int jb = blockIdx.x & 15;  // 0..15 -> cols 16jb..16jb+15 and +256
    const int t  = threadIdx.x;      // 0..255

    __shared__ __align__(16) float4 Af[32 * S4];  // 32 A-rows
    __shared__ __align__(16) float4 Bf[32 * S4];  // B rows 0..15: col 16jb+r; 16..31: +256
    __shared__ float sqB[32];
    __shared__ float red[3][4];

    // stage A and B tiles (coalesced float4, swizzled writes) — round-4 pattern
#pragma unroll
    for (int p = 0; p < 8; ++p) {
        const int idx = p * 256 + t;
        const int row = idx >> 6, c4 = idx & 63;
        Af[lds4(row, c4)] = reinterpret_cast<const float4*>(batch_row(h1, h2, ib * 32 + row))[c4];
        const int col = jb * 16 + ((row < 16) ? row : row + 240);   // +240 == -16+256
        Bf[lds4(row, c4)] = reinterpret_cast<const float4*>(batch_row(h1, h2, col))[c4];
    }
    __syncthreads();

    // per-B-row squared norms from LDS (8 lanes per row, ~200 cycles)
    {
        const int row = t >> 3, sub = t & 7;
        float4 a4 = make_float4(0.f, 0.f, 0.f, 0.f);
#pragma unroll
        for (int i = 0; i < 8; ++i) {
            const float4 v = Bf[lds4(row, sub + 8 * i)];
            a4.x = fmaf(v.x, v.x, a4.x); a4.y = fmaf(v.y, v.y, a4.y);
            a4.z = fmaf(v.z, v.z, a4.z); a4.w = fmaf(v.w, v.w, a4.w);
        }
        float s = hsum4(a4);
        s += __shfl_xor(s, 1); s += __shfl_xor(s, 2); s += __shfl_xor(s, 4);
        if (sub == 0) {
            sqB[row] = s;
            if (ib == 0) sq[jb * 16 + ((row < 16) ? row : row + 240)] = s;  // each col once
        }
    }
    __syncthreads();

    // main loop: identical shape to round-4 proven engine (2x2 micro-tile)
    const int ty = t >> 4;           // 0..15 -> A rows 2ty, 2ty+1
    const int tx = t & 15;           // 0..15 -> B rows 2tx, 2tx+1
    const int ba = (2 * ty) * S4;
    const int bb = (2 * tx) * S4;

    float4 c00 = make_float4(0.f, 0.f, 0.f, 0.f), c01 = c00, c10 = c00, c11 = c00;
#pragma unroll 8
    for (int k4 = 0; k4 < 64; ++k4) {
        const int ea = k4 ^ ty;      // mask for A rows 2ty,2ty+1
        const int eb = k4 ^ tx;      // mask for B rows 2tx,2tx+1
        const float4 a0 = Af[ba + ea];
        const float4 a1 = Af[ba + S4 + ea];
        const float4 b0 = Bf[bb + eb];
        const float4 b1 = Bf[bb + S4 + eb];
        c00.x = fmaf(a0.x, b0.x, c00.x); c00.y = fmaf(a0.y, b0.y, c00.y);
        c00.z = fmaf(a0.z, b0.z, c00.z); c00.w = fmaf(a0.w, b0.w, c00.w);
        c01.x = fmaf(a0.x, b1.x, c01.x); c01.y = fmaf(a0.y, b1.y, c01.y);
        c01.z = fmaf(a0.z, b1.z, c01.z); c01.w = fmaf(a0.w, b1.w, c01.w);
        c10.x = fmaf(a1.x, b0.x, c10.x); c10.y = fmaf(a1.y, b0.y, c10.y);
        c10.z = fmaf(a1.z, b0.z, c10.z); c10.w = fmaf(a1.w, b0.w, c10.w);
        c11.x = fmaf(a1.x, b1.x, c11.x); c11.y = fmaf(a1.y, b1.y, c11.y);
        c11.z = fmaf(a1.z, b1.z, c11.z); c11.w = fmaf(a1.w, b1.w, c11.w);
    }
    const float s00 = hsum4(c00), s01 = hsum4(c01);
    const float s10 = hsum4(c10), s11 = hsum4(c11);

    // pair exchange: partner thread (lane^8) holds dot(i, j^256) for same i
    const float p00 = __shfl_xor(s00, 8);
    const float p01 = __shfl_xor(s01, 8);
    const float p10 = __shfl_xor(s10, 8);
    const float p11 = __shfl_xor(s11, 8);
    const int r0 = 2 * tx, r1 = 2 * tx + 1;
    const int q0 = 2 * (tx ^ 8), q1 = q0 + 1;
    const float dq0 = sqB[r0] - sqB[q0];
    const float dq1 = sqB[r1] - sqB[q1];

    float srel = 0.f, crel = 0.f, good = 0.f;
    {
        const float tv = fmaxf(dq0 - 2.f * (s00 - p00) + 1.f, 0.f);  // (2ty,   c0)
        srel += (tv > 1e-5f) ? tv : 0.f; crel += (tv > 1e-5f); good += (tv < 1e-5f);
    }
    {
        const float tv = fmaxf(dq1 - 2.f * (s01 - p01) + 1.f, 0.f);  // (2ty,   c1)
        srel += (tv > 1e-5f) ? tv : 0.f; crel += (tv > 1e-5f); good += (tv < 1e-5f);
    }
    {
        const float tv = fmaxf(dq0 - 2.f * (s10 - p10) + 1.f, 0.f);  // (2ty+1, c0)
        srel += (tv > 1e-5f) ? tv : 0.f; crel += (tv > 1e-5f); good += (tv < 1e-5f);
    }
    {
        const float tv = fmaxf(dq1 - 2.f * (s11 - p11) + 1.f, 0.f);  // (2ty+1, c1)
        srel += (tv > 1e-5f) ? tv : 0.f; crel += (tv > 1e-5f); good += (tv < 1e-5f);
    }

#pragma unroll
    for (int off = 32; off > 0; off >>= 1) {
        srel += __shfl_down(srel, off);
        crel += __shfl_down(crel, off);
        good += __shfl_down(good, off);
    }
    const int w = t >> 6;
    if ((t & 63) == 0) { red[0][w] = srel; red[1][w] = crel; red[2][w] = good; }
    __syncthreads();
    if (t == 0) {
        reinterpret_cast<float4*>(partials)[blockIdx.x] =
            make_float4(red[0][0] + red[0][1] + red[0][2] + red[0][3],
                        red[1][0] + red[1][1] + red[1][2] + red[1][3],
                        red[2][0] + red[2][1] + red[2][2] + red[2][3], 0.f);
    }
}

// --- K2: final reduction + all 5 outputs ----------------------------------
__global__ __launch_bounds__(512) void finalize_kernel(const float* __restrict__ sq,
                                                       const float* __restrict__ partials,
                                                       float* __restrict__ out) {
    const int t = threadIdx.x;   // 0..511
    float4 pv = make_float4(0.f, 0.f, 0.f, 0.f);
    if (t < 256) pv = reinterpret_cast<const float4*>(partials)[t];
    float s = pv.x, c = pv.y, g = pv.z, q = sq[t];
#pragma unroll
    for (int off = 32; off > 0; off >>= 1) {
        s += __shfl_down(s, off);
        c += __shfl_down(c, off);
        g += __shfl_down(g, off);
        q += __shfl_down(q, off);
    }
    __shared__ float red[4][8];
    const int w = t >> 6;
    if ((t & 63) == 0) { red[0][w] = s; red[1][w] = c; red[2][w] = g; red[3][w] = q; }
    __syncthreads();
    if (t == 0) {
        float ss = 0.f, cc = 0.f, gg = 0.f, qq = 0.f;
#pragma unroll
        for (int k = 0; k < 8; ++k) { ss += red[0][k]; cc += red[1][k]; gg += red[2][k]; qq += red[3][k]; }
        const float mean_sq  = qq / 512.0f;
        const float mean_rel = ss / cc;
        const float goodTot  = 133955584.0f + gg;   // (512^3 - 512^2) + good_masked
        out[0] = mean_rel + 1e-4f * mean_sq;        // loss
        out[1] = 0.0f;                              // mean(differences): exact cancellation
        out[2] = goodTot;                           // good
        out[3] = 134217728.0f - goodTot;            // bad
        out[4] = sqrtf(mean_sq);                    // sqrt(mean norm^2)
    }
}

extern "C" void kernel_launch(void* const* d_in, const int* in_sizes, int n_in,
                              void* d_out, int out_size, void* d_ws, size_t ws_size,
                              hipStream_t stream) {
    (void)in_sizes; (void)n_in; (void)out_size; (void)ws_size;
    const float* h1 = (const float*)d_in[0];
    const float* h2 = (const float*)d_in[1];
    // d_in[2] (h3) unused by the reference forward.
    char* ws = (char*)d_ws;
    float* sq       = (float*)ws;              // 512 floats
    float* partials = (float*)(ws + 4096);     // 256 x float4
    float* out      = (float*)d_out;

    gramstats_kernel<<<256, 256, 0, stream>>>(h1, h2, sq, partials);
    finalize_kernel <<<1,   512, 0, stream>>>(sq, partials, out);
}

// Round 7
// 11.628 us; speedup vs baseline: 1.9410x; 1.2602x over previous
//
#include <hip/hip_runtime.h>
#include <math.h>

// BatchAllTripletLoss — bf16-MFMA Gram engine, G-free, pair-fused.
// batch = concat(h1,h2) : (512, 256) f32.
// Masked triplet only at k=j^256:
//   t(i,j) = relu((sq_j - sq_jp) - 2*(dot_ij - dot_ijp) + 1)   [sq_i cancels]
// outputs: loss, mean(differences)=0 (exact), good, bad, sqrt(mean(sq))
//
// Lessons encoded:
//  r3: no __threadfence/atomic finalize (~40us) -> tiny second kernel.
//  r5: keep 4-wave blocks, 256 blocks (1/CU).
//  r6: f32 VALU engine floor ~10us (LDS 4B/MAC) -> switch dot engine to MFMA.
// Precision: inputs bf16-rounded (RNE), accum f32; sq kept f32 from original
// values. diff error ~0.1 vs spread ~55 -> ~150 count flips of 262k, well
// under the 2% per-output thresholds (bad ~131k -> thr ~2.6e3).
//
// MFMA 16x16x32 bf16 layouts (measured, m89/m91):
//   A: lane l holds row l&15, k = 8*(l>>4)..+7   (s16x8, 4 VGPR)
//   B: lane l holds col l&15, same k chunk       (identical load pattern)
//   D: col = lane&15, row = (lane>>4)*4 + reg
// LDS tile [32 rows][256 bf16] with k-group swizzle g^=(row&7) -> 2-way max.

typedef short s16x8 __attribute__((ext_vector_type(8)));
typedef float f32x4 __attribute__((ext_vector_type(4)));

__device__ __forceinline__ const float* batch_row(const float* __restrict__ h1,
                                                  const float* __restrict__ h2,
                                                  int r) {
    return (r < 256) ? (h1 + (size_t)r * 256) : (h2 + (size_t)(r - 256) * 256);
}

__device__ __forceinline__ unsigned short f2bf(float f) {   // RNE f32->bf16
    union { float f; unsigned u; } v; v.f = f;
    const unsigned r = v.u + 0x7FFFu + ((v.u >> 16) & 1u);
    return (unsigned short)(r >> 16);
}

__device__ __forceinline__ s16x8 pack8(float4 lo, float4 hi) {
    s16x8 p;
    p[0] = (short)f2bf(lo.x); p[1] = (short)f2bf(lo.y);
    p[2] = (short)f2bf(lo.z); p[3] = (short)f2bf(lo.w);
    p[4] = (short)f2bf(hi.x); p[5] = (short)f2bf(hi.y);
    p[6] = (short)f2bf(hi.z); p[7] = (short)f2bf(hi.w);
    return p;
}

// --- K1: MFMA Gram + pair stats + f32 sq emission -------------------------
__global__ __launch_bounds__(256) void gramstats_kernel(const float* __restrict__ h1,
                                                        const float* __restrict__ h2,
                                                        float* __restrict__ sq,
                                                        float* __restrict__ partials) {
    const int ib = blockIdx.x >> 4;  // 0..15 -> A rows 32ib..32ib+31
    const int jb = blockIdx.x & 15;  // 0..15 -> cols 16jb..+15 (rows 0-15) and +256 (rows 16-31)
    const int t  = threadIdx.x;      // 0..255

    __shared__ __align__(16) unsigned short tileA[32 * 256];  // 16 KB
    __shared__ __align__(16) unsigned short tileB[32 * 256];  // 16 KB
    __shared__ float pairD[32 * 17];                          // pair dots (padded)
    __shared__ float sqB[32];
    __shared__ float red[3][4];

    // --- stage: f32 global -> bf16 LDS (swizzled); f32 sq on the fly ------
    {
        const int row = t >> 3;      // 0..31
        const int seg = t & 7;       // 0..7 -> k-groups 4seg..4seg+3
        const float4* Ap = reinterpret_cast<const float4*>(batch_row(h1, h2, ib * 32 + row));
        const int bcol = jb * 16 + ((row < 16) ? row : row + 240);   // +240 == -16+256
        const float4* Bp = reinterpret_cast<const float4*>(batch_row(h1, h2, bcol));
        float sacc = 0.f;
#pragma unroll
        for (int gi = 0; gi < 4; ++gi) {
            const int g  = seg * 4 + gi;              // k-group 0..31 (8 bf16 each)
            const int gs = (g ^ (row & 7)) * 8;       // swizzled element offset
            const float4 al = Ap[2 * g], ah = Ap[2 * g + 1];
            *reinterpret_cast<s16x8*>(&tileA[row * 256 + gs]) = pack8(al, ah);
            const float4 bl = Bp[2 * g], bh = Bp[2 * g + 1];
            *reinterpret_cast<s16x8*>(&tileB[row * 256 + gs]) = pack8(bl, bh);
            sacc += bl.x * bl.x + bl.y * bl.y + bl.z * bl.z + bl.w * bl.w
                  + bh.x * bh.x + bh.y * bh.y + bh.z * bh.z + bh.w * bh.w;
        }
        sacc += __shfl_xor(sacc, 1);
        sacc += __shfl_xor(sacc, 2);
        sacc += __shfl_xor(sacc, 4);
        if (seg == 0) {
            sqB[row] = sacc;
            if (ib == 0) sq[bcol] = sacc;             // each col exactly once
        }
    }
    __syncthreads();

    // --- MFMA: wave (rh,ch) computes 16x16 dot tile -----------------------
    const int lane = t & 63, w = t >> 6;
    const int rh = w >> 1;               // A row-half: rows rh*16..+15
    const int ch = w & 1;                // 0: j cols (B rows 0-15), 1: pairs (16-31)
    const int ar = rh * 16 + (lane & 15);
    const int br = ch * 16 + (lane & 15);
    const int kc = lane >> 4;            // 0..3
    f32x4 acc = {0.f, 0.f, 0.f, 0.f};
#pragma unroll
    for (int s = 0; s < 8; ++s) {
        const int ga = ((s * 4 + kc) ^ (ar & 7)) * 8;
        const int gb = ((s * 4 + kc) ^ (br & 7)) * 8;
        const s16x8 av = *reinterpret_cast<const s16x8*>(&tileA[ar * 256 + ga]);
        const s16x8 bv = *reinterpret_cast<const s16x8*>(&tileB[br * 256 + gb]);
        acc = __builtin_amdgcn_mfma_f32_16x16x32_bf16(av, bv, acc, 0, 0, 0);
    }

    // --- pair exchange: ch=1 publishes dot(i, j^256) ----------------------
    const int n  = lane & 15;            // D col
    const int i0 = (lane >> 4) * 4;      // D row base
    if (ch == 1) {
#pragma unroll
        for (int r = 0; r < 4; ++r)
            pairD[(rh * 16 + i0 + r) * 17 + n] = acc[r];
    }
    __syncthreads();

    float srel = 0.f, crel = 0.f, good = 0.f;
    if (ch == 0) {
        const float dsq = sqB[n] - sqB[n + 16];      // sq_j - sq_jpair
#pragma unroll
        for (int r = 0; r < 4; ++r) {
            const float dotp = pairD[(rh * 16 + i0 + r) * 17 + n];
            const float diff = dsq - 2.f * (acc[r] - dotp);
            const float tj = fmaxf(diff + 1.f, 0.f); // entry (i, j)
            const float tp = fmaxf(1.f - diff, 0.f); // entry (i, j^256)
            srel += ((tj > 1e-5f) ? tj : 0.f) + ((tp > 1e-5f) ? tp : 0.f);
            crel += (float)((tj > 1e-5f) + (tp > 1e-5f));
            good += (float)((tj < 1e-5f) + (tp < 1e-5f));
        }
    }

#pragma unroll
    for (int off = 32; off > 0; off >>= 1) {
        srel += __shfl_down(srel, off);
        crel += __shfl_down(crel, off);
        good += __shfl_down(good, off);
    }
    if ((t & 63) == 0) { red[0][w] = srel; red[1][w] = crel; red[2][w] = good; }
    __syncthreads();
    if (t == 0) {
        reinterpret_cast<float4*>(partials)[blockIdx.x] =
            make_float4(red[0][0] + red[0][1] + red[0][2] + red[0][3],
                        red[1][0] + red[1][1] + red[1][2] + red[1][3],
                        red[2][0] + red[2][1] + red[2][2] + red[2][3], 0.f);
    }
}

// --- K2: final reduction + all 5 outputs ----------------------------------
__global__ __launch_bounds__(512) void finalize_kernel(const float* __restrict__ sq,
                                                       const float* __restrict__ partials,
                                                       float* __restrict__ out) {
    const int t = threadIdx.x;   // 0..511
    float4 pv = make_float4(0.f, 0.f, 0.f, 0.f);
    if (t < 256) pv = reinterpret_cast<const float4*>(partials)[t];
    float s = pv.x, c = pv.y, g = pv.z, q = sq[t];
#pragma unroll
    for (int off = 32; off > 0; off >>= 1) {
        s += __shfl_down(s, off);
        c += __shfl_down(c, off);
        g += __shfl_down(g, off);
        q += __shfl_down(q, off);
    }
    __shared__ float red[4][8];
    const int w = t >> 6;
    if ((t & 63) == 0) { red[0][w] = s; red[1][w] = c; red[2][w] = g; red[3][w] = q; }
    __syncthreads();
    if (t == 0) {
        float ss = 0.f, cc = 0.f, gg = 0.f, qq = 0.f;
#pragma unroll
        for (int k = 0; k < 8; ++k) { ss += red[0][k]; cc += red[1][k]; gg += red[2][k]; qq += red[3][k]; }
        const float mean_sq  = qq / 512.0f;
        const float mean_rel = ss / cc;
        const float goodTot  = 133955584.0f + gg;   // (512^3 - 512^2) + good_masked
        out[0] = mean_rel + 1e-4f * mean_sq;        // loss
        out[1] = 0.0f;                              // mean(differences): exact cancellation
        out[2] = goodTot;                           // good
        out[3] = 134217728.0f - goodTot;            // bad
        out[4] = sqrtf(mean_sq);                    // sqrt(mean norm^2)
    }
}

extern "C" void kernel_launch(void* const* d_in, const int* in_sizes, int n_in,
                              void* d_out, int out_size, void* d_ws, size_t ws_size,
                              hipStream_t stream) {
    (void)in_sizes; (void)n_in; (void)out_size; (void)ws_size;
    const float* h1 = (const float*)d_in[0];
    const float* h2 = (const float*)d_in[1];
    // d_in[2] (h3) unused by the reference forward.
    char* ws = (char*)d_ws;
    float* sq       = (float*)ws;              // 512 floats
    float* partials = (float*)(ws + 4096);     // 256 x float4
    float* out      = (float*)d_out;

    gramstats_kernel<<<256, 256, 0, stream>>>(h1, h2, sq, partials);
    finalize_kernel <<<1,   512, 0, stream>>>(sq, partials, out);
}

// Round 8
// 11.207 us; speedup vs baseline: 2.0139x; 1.0375x over previous
//
#include <hip/hip_runtime.h>
#include <math.h>

// BatchAllTripletLoss — bf16-MFMA Gram engine v2: in-register pair exchange.
// batch = concat(h1,h2) : (512, 256) f32.
// Masked triplet only at k=j^256:
//   t(i,j) = relu((sq_j - sq_jp) - 2*(dot_ij - dot_ijp) + 1)   [sq_i cancels]
// outputs: loss, mean(differences)=0 (exact), good, bad, sqrt(mean(sq))
//
// Lessons encoded:
//  r3: no __threadfence/atomic finalize (~40us) -> tiny second kernel.
//  r5: keep >=4 waves/CU; 256 blocks (1/CU).
//  r6: f32 VALU engine floor ~10us -> MFMA dot engine (r7: 11.6us).
//  r7->r8: B-tile = 8 j-cols + their 8 pairs within ONE 16-wide MFMA tile;
//          pair dot = __shfl_xor(acc, 8) (D col = lane&15). Kills the pairD
//          LDS bounce + the idle half of the epilogue. A-tile 64 rows,
//          grid = 8 x 32 = 256. Finalize slimmed to one wave.
//
// MFMA 16x16x32 bf16 layouts (measured, m89/m91):
//   A frag: lane l holds row l&15, k chunk 8*(l>>4)..+7   (s16x8)
//   B frag: lane l holds col l&15, same k chunk
//   D frag: col = lane&15, row = (lane>>4)*4 + reg
// LDS tiles [rows][256 bf16], k-group swizzle g^=(row&7) -> <=2-way (free).

typedef short s16x8 __attribute__((ext_vector_type(8)));
typedef float f32x4 __attribute__((ext_vector_type(4)));

__device__ __forceinline__ const float* batch_row(const float* __restrict__ h1,
                                                  const float* __restrict__ h2,
                                                  int r) {
    return (r < 256) ? (h1 + (size_t)r * 256) : (h2 + (size_t)(r - 256) * 256);
}

__device__ __forceinline__ unsigned short f2bf(float f) {   // RNE f32->bf16
    union { float f; unsigned u; } v; v.f = f;
    const unsigned r = v.u + 0x7FFFu + ((v.u >> 16) & 1u);
    return (unsigned short)(r >> 16);
}

__device__ __forceinline__ s16x8 pack8(float4 lo, float4 hi) {
    s16x8 p;
    p[0] = (short)f2bf(lo.x); p[1] = (short)f2bf(lo.y);
    p[2] = (short)f2bf(lo.z); p[3] = (short)f2bf(lo.w);
    p[4] = (short)f2bf(hi.x); p[5] = (short)f2bf(hi.y);
    p[6] = (short)f2bf(hi.z); p[7] = (short)f2bf(hi.w);
    return p;
}

__device__ __forceinline__ float hsum4(float4 v) { return (v.x + v.y) + (v.z + v.w); }

// --- K1: MFMA Gram + pair stats + f32 sq emission -------------------------
__global__ __launch_bounds__(256) void gramstats_kernel(const float* __restrict__ h1,
                                                        const float* __restrict__ h2,
                                                        float* __restrict__ sq,
                                                        float* __restrict__ partials) {
    const int ib = blockIdx.x >> 5;  // 0..7  -> A rows 64ib..64ib+63
    const int jb = blockIdx.x & 31;  // 0..31 -> B cols 8jb..+7 (rows 0-7) and +256 (rows 8-15)
    const int t  = threadIdx.x;      // 0..255

    __shared__ __align__(16) unsigned short tileA[64 * 256];  // 32 KB
    __shared__ __align__(16) unsigned short tileB[16 * 256];  //  8 KB
    __shared__ float sqB[16];
    __shared__ float red[3][4];

    // --- stage A: 64 rows, f32 -> bf16, swizzled (8 groups/thread) --------
#pragma unroll
    for (int p = 0; p < 8; ++p) {
        const int idx = p * 256 + t;
        const int row = idx >> 5, g = idx & 31;          // 32 k-groups of 8 per row
        const float4* Ap = reinterpret_cast<const float4*>(batch_row(h1, h2, ib * 64 + row));
        const int gs = (g ^ (row & 7)) * 8;
        *reinterpret_cast<s16x8*>(&tileA[row * 256 + gs]) = pack8(Ap[2 * g], Ap[2 * g + 1]);
    }
    // --- stage B: 16 rows (8 j-cols + 8 pairs) + f32 sq on the fly --------
#pragma unroll
    for (int p = 0; p < 2; ++p) {
        const int idx = p * 256 + t;
        const int row = idx >> 5, g = idx & 31;
        const int col = jb * 8 + (row & 7) + ((row & 8) << 5);   // +256 for rows 8-15
        const float4* Bp = reinterpret_cast<const float4*>(batch_row(h1, h2, col));
        const float4 lo = Bp[2 * g], hi = Bp[2 * g + 1];
        const int gs = (g ^ (row & 7)) * 8;
        *reinterpret_cast<s16x8*>(&tileB[row * 256 + gs]) = pack8(lo, hi);
        float s = lo.x * lo.x + lo.y * lo.y + lo.z * lo.z + lo.w * lo.w
                + hi.x * hi.x + hi.y * hi.y + hi.z * hi.z + hi.w * hi.w;
        s += __shfl_xor(s, 1);  s += __shfl_xor(s, 2);  s += __shfl_xor(s, 4);
        s += __shfl_xor(s, 8);  s += __shfl_xor(s, 16);         // 32-lane group reduce
        if ((t & 31) == 0) {
            sqB[row] = s;
            if (ib == 0) sq[col] = s;                            // each col exactly once
        }
    }
    __syncthreads();

    // --- MFMA: wave rh computes A rows rh*16..+15 x all 16 B cols ---------
    const int lane = t & 63, w = t >> 6;   // w = rh 0..3
    const int ar = w * 16 + (lane & 15);
    const int br = lane & 15;
    const int kc = lane >> 4;              // 0..3
    f32x4 acc = {0.f, 0.f, 0.f, 0.f};
#pragma unroll
    for (int s = 0; s < 8; ++s) {
        const int ga = ((s * 4 + kc) ^ (ar & 7)) * 8;
        const int gb = ((s * 4 + kc) ^ (br & 7)) * 8;
        const s16x8 av = *reinterpret_cast<const s16x8*>(&tileA[ar * 256 + ga]);
        const s16x8 bv = *reinterpret_cast<const s16x8*>(&tileB[br * 256 + gb]);
        acc = __builtin_amdgcn_mfma_f32_16x16x32_bf16(av, bv, acc, 0, 0, 0);
    }

    // --- stats: pair dot lives in lane^8 (D col = lane&15) ----------------
    const int n = lane & 15;
    const float dsq = sqB[n] - sqB[n ^ 8];               // sq_col - sq_pair
    float srel = 0.f, crel = 0.f, good = 0.f;
#pragma unroll
    for (int r = 0; r < 4; ++r) {
        const float dotp = __shfl_xor(acc[r], 8);        // dot(i, pair col)
        const float diff = dsq - 2.f * (acc[r] - dotp);
        const float tv = fmaxf(diff + 1.f, 0.f);
        srel += (tv > 1e-5f) ? tv : 0.f;
        crel += (tv > 1e-5f);
        good += (tv < 1e-5f);
    }

#pragma unroll
    for (int off = 32; off > 0; off >>= 1) {
        srel += __shfl_down(srel, off);
        crel += __shfl_down(crel, off);
        good += __shfl_down(good, off);
    }
    if ((t & 63) == 0) { red[0][w] = srel; red[1][w] = crel; red[2][w] = good; }
    __syncthreads();
    if (t == 0) {
        reinterpret_cast<float4*>(partials)[blockIdx.x] =
            make_float4(red[0][0] + red[0][1] + red[0][2] + red[0][3],
                        red[1][0] + red[1][1] + red[1][2] + red[1][3],
                        red[2][0] + red[2][1] + red[2][2] + red[2][3], 0.f);
    }
}

// --- K2: single-wave finalize + all 5 outputs -----------------------------
__global__ __launch_bounds__(64) void finalize_kernel(const float* __restrict__ sq,
                                                      const float* __restrict__ partials,
                                                      float* __restrict__ out) {
    const int t = threadIdx.x;   // 0..63
    float s = 0.f, c = 0.f, g = 0.f, q = 0.f;
    const float4* P = reinterpret_cast<const float4*>(partials);
#pragma unroll
    for (int p = 0; p < 4; ++p) {                 // 256 partials
        const float4 v = P[t + 64 * p];
        s += v.x; c += v.y; g += v.z;
    }
    const float4* S = reinterpret_cast<const float4*>(sq);
#pragma unroll
    for (int p = 0; p < 2; ++p)                   // 512 sq values
        q += hsum4(S[t + 64 * p]);
#pragma unroll
    for (int off = 32; off > 0; off >>= 1) {
        s += __shfl_down(s, off);
        c += __shfl_down(c, off);
        g += __shfl_down(g, off);
        q += __shfl_down(q, off);
    }
    if (t == 0) {
        const float mean_sq  = q / 512.0f;
        const float mean_rel = s / c;
        const float goodTot  = 133955584.0f + g;    // (512^3 - 512^2) + good_masked
        out[0] = mean_rel + 1e-4f * mean_sq;        // loss
        out[1] = 0.0f;                              // mean(differences): exact cancellation
        out[2] = goodTot;                           // good
        out[3] = 134217728.0f - goodTot;            // bad
        out[4] = sqrtf(mean_sq);                    // sqrt(mean norm^2)
    }
}

extern "C" void kernel_launch(void* const* d_in, const int* in_sizes, int n_in,
                              void* d_out, int out_size, void* d_ws, size_t ws_size,
                              hipStream_t stream) {
    (void)in_sizes; (void)n_in; (void)out_size; (void)ws_size;
    const float* h1 = (const float*)d_in[0];
    const float* h2 = (const float*)d_in[1];
    // d_in[2] (h3) unused by the reference forward.
    char* ws = (char*)d_ws;
    float* sq       = (float*)ws;              // 512 floats
    float* partials = (float*)(ws + 4096);     // 256 x float4
    float* out      = (float*)d_out;

    gramstats_kernel<<<256, 256, 0, stream>>>(h1, h2, sq, partials);
    finalize_kernel <<<1,   64,  0, stream>>>(sq, partials, out);
}